// Round 8
// baseline (749.347 us; speedup 1.0000x reference)
//
#include <hip/hip_runtime.h>

// MoE switch layer: B=8, N=2048, D=1024, E=8, DFF=4096, CAP=320
#define Bq 8
#define Nq 2048
#define Dq 1024
#define Eq 8
#define DFFq 4096
#define CAPq 320
#define Mq (Bq * CAPq)   // 2560 rows per expert
#define Tq (Bq * Nq)     // 16384 tokens

typedef __attribute__((ext_vector_type(8))) short bf16x8;
typedef __attribute__((ext_vector_type(4))) float f32x4;
typedef __attribute__((ext_vector_type(16))) float f32x16;

static __device__ __forceinline__ unsigned short f2bf(float f) {
    union { float f; unsigned u; } v;
    v.f = f;
    unsigned r = v.u + 0x7fffu + ((v.u >> 16) & 1u);   // RNE
    return (unsigned short)(r >> 16);
}

static __device__ __forceinline__ void gload_lds16(const void* g, void* l) {
    __builtin_amdgcn_global_load_lds(
        (const __attribute__((address_space(1))) unsigned int*)g,
        (__attribute__((address_space(3))) unsigned int*)l, 16, 0, 0);
}

// ---------------- routing: logits -> softmax -> argmax/gate ----------------
__global__ __launch_bounds__(256) void route_kernel(
    const float* __restrict__ tok, const float* __restrict__ Wg,
    int* __restrict__ eidx, float* __restrict__ gate)
{
    int wv = threadIdx.x >> 6, lane = threadIdx.x & 63;
    int t = blockIdx.x * 4 + wv;
    const float* tp = tok + (size_t)t * Dq;
    float acc[8] = {0.f,0.f,0.f,0.f,0.f,0.f,0.f,0.f};
    for (int it = 0; it < Dq / 64; ++it) {
        int d = it * 64 + lane;
        float x = tp[d];
        const float4* w = (const float4*)(Wg + (size_t)d * 8);
        float4 w0 = w[0], w1 = w[1];
        acc[0] += x * w0.x; acc[1] += x * w0.y; acc[2] += x * w0.z; acc[3] += x * w0.w;
        acc[4] += x * w1.x; acc[5] += x * w1.y; acc[6] += x * w1.z; acc[7] += x * w1.w;
    }
#pragma unroll
    for (int e = 0; e < 8; ++e)
#pragma unroll
        for (int off = 32; off; off >>= 1)
            acc[e] += __shfl_xor(acc[e], off, 64);
    if (lane == 0) {
        float m = acc[0]; int bi = 0;
#pragma unroll
        for (int e = 1; e < 8; ++e) if (acc[e] > m) { m = acc[e]; bi = e; }
        float s = 0.f;
#pragma unroll
        for (int e = 0; e < 8; ++e) s += expf(acc[e] - m);
        eidx[t] = bi;
        gate[t] = 1.0f / s;   // max prob
    }
}

// ------------- slot assignment + zero dropped-token output rows ------------
__global__ __launch_bounds__(64) void slot_kernel(
    const int* __restrict__ eidx, int* __restrict__ tfs,
    float* __restrict__ out)
{
    int b = blockIdx.x >> 3, e = blockIdx.x & 7;
    int lane = threadIdx.x;
    const int* ip = eidx + (size_t)b * Nq;
    int base = (e * Bq + b) * CAPq;
    int cnt = 0;
    for (int it = 0; it < Nq / 64; ++it) {
        int n = it * 64 + lane;
        bool my = (ip[n] == e);
        unsigned long long mask = __ballot(my);
        if (my) {
            int pos = cnt + __popcll(mask & ((1ull << lane) - 1ull));
            if (pos < CAPq) {
                tfs[base + pos] = b * Nq + n;
            } else {
                // dropped token: its output row must be zero
                float4 z = {0.f, 0.f, 0.f, 0.f};
                float4* op = (float4*)(out + (size_t)(b * Nq + n) * Dq);
                for (int q = 0; q < Dq / 4; ++q) op[q] = z;
            }
        }
        cnt += __popcll(mask);
    }
}

// ------------- dispatch: gather token rows -> bf16 expert buffers ----------
__global__ __launch_bounds__(128) void dispatch_kernel(
    const float* __restrict__ tok, const int* __restrict__ tfs,
    unsigned short* __restrict__ X)
{
    int r = blockIdx.x;          // 0 .. E*B*CAP-1
    int t = tfs[r];
    int d0 = threadIdx.x * 8;
    unsigned short o[8];
    if (t < 0) {
#pragma unroll
        for (int k = 0; k < 8; ++k) o[k] = 0;
    } else {
        const float4* p = (const float4*)(tok + (size_t)t * Dq + d0);
        float4 a = p[0], b = p[1];
        o[0]=f2bf(a.x); o[1]=f2bf(a.y); o[2]=f2bf(a.z); o[3]=f2bf(a.w);
        o[4]=f2bf(b.x); o[5]=f2bf(b.y); o[6]=f2bf(b.z); o[7]=f2bf(b.w);
    }
    *(uint4*)(X + (size_t)r * Dq + d0) = *(const uint4*)o;
}

// ------- weight transpose+convert: in [E][R][C] f32 -> out [E][C][R] bf16 --
__global__ __launch_bounds__(256) void transpose_cvt(
    const float* __restrict__ in, unsigned short* __restrict__ out,
    int R, int C)
{
    __shared__ float tile[32][33];
    int e = blockIdx.z;
    int c0 = blockIdx.x * 32, r0 = blockIdx.y * 32;
    int tx = threadIdx.x & 31, ty = threadIdx.x >> 5;
    const float* ip = in + (size_t)e * R * C;
#pragma unroll
    for (int rr = 0; rr < 4; ++rr)
        tile[ty + rr * 8][tx] = ip[(size_t)(r0 + ty + rr * 8) * C + c0 + tx];
    __syncthreads();
    unsigned short* op = out + (size_t)e * R * C;
#pragma unroll
    for (int rr = 0; rr < 4; ++rr)
        op[(size_t)(c0 + ty + rr * 8) * R + r0 + tx] = f2bf(tile[tx][ty + rr * 8]);
}

// ========== big-wave 256x256 NT GEMM: 4 waves, per-wave 128x128 ============
// C[M][N] = A[M][K]*Bt[N][K]^T per expert, mfma_f32_32x32x16_bf16.
// 256 thr = 4 waves (2M x 2N), per-wave 128x128 = 16 acc tiles (256 VGPR ->
// 1 wave/SIMD; all latency hiding is IN-WAVE). LDS: A/B [256][64] bf16
// double-buffered = 128 KiB. Loop: issue stage(kt+1) (16 gload_lds16),
// compute 4 k-slices (8 ds_read_b128 + 16 MFMA each; compiler emits counted
// lgkm), then vmcnt(0) (covered by ~2070 cyc of MFMA) + barrier.
// Swizzle: byte ^= (row&7)<<4 on reads, pre-swizzled global source (linear
// gload_lds dest). <=8 lanes per 16B slot-column -> conflict-free.
// MODE 0: H = relu(C) bf16.  MODE 1: scatter rows to Out with gate.
template <int MODE, int Ndim, int Kdim>
__global__ __launch_bounds__(256, 1) void gemmw(
    const unsigned short* __restrict__ A,   // [E][M][K] bf16
    const unsigned short* __restrict__ Bt,  // [E][N][K] bf16
    unsigned short* __restrict__ Hout,      // [E][M][N] bf16  (MODE 0)
    float* __restrict__ Out,                // [T][D] f32      (MODE 1)
    const int* __restrict__ tfs,            // [E][M]
    const float* __restrict__ gate)         // [T]
{
    constexpr int NKT = Kdim / 64;           // K-tiles
    constexpr int NTB = Ndim / 256;
    constexpr int MT  = Mq / 256;            // 10
    constexpr int NWG = MT * NTB * Eq;       // multiple of 8

    __shared__ __align__(16) unsigned short As[2][256 * 64];  // 64 KiB
    __shared__ __align__(16) unsigned short Bs[2][256 * 64];  // 64 KiB
    __shared__ int   t_lds[256];
    __shared__ float g_lds[256];

    // XCD-aware bijective swizzle (NWG % 8 == 0)
    int flat = blockIdx.x;
    int wg = (flat & 7) * (NWG / 8) + (flat >> 3);
    int e   = wg / (MT * NTB);
    int rem = wg - e * (MT * NTB);
    int mb = rem / NTB, nb = rem - mb * NTB;
    int m0 = mb * 256, n0 = nb * 256;

    const char* Ae = (const char*)(A  + (size_t)e * Mq * Kdim + (size_t)m0 * Kdim);
    const char* Be = (const char*)(Bt + (size_t)e * Ndim * Kdim + (size_t)n0 * Kdim);

    const int tid = threadIdx.x;
    if (MODE == 1) {
        int t = tfs[e * Mq + m0 + tid];
        t_lds[tid] = t;
        g_lds[tid] = (t >= 0) ? gate[t] : 0.f;
        __syncthreads();
    }

    const int l  = tid & 63;
    const int wv = tid >> 6;
    const int wr = wv >> 1, wc = wv & 1;     // 2M x 2N waves, per-wave 128x128
    const int lr = l & 31;                   // row-in-tile (A) / col-in-tile (B)
    const int kg = l >> 5;                   // k-group (0/1): k = ks*16 + kg*8 + j
    const int swz = (l & 7) << 4;            // row&7 == l&7 for all frag rows

    // fragment base byte offsets within a buffer ([256][64] bf16, 128B rows)
    const int abase = (wr * 128 + lr) * 128;   // + mt*32rows*128 + ((ks*32+kg*16)^swz)
    const int bbase = (wc * 128 + lr) * 128;

    // staging: [256][64] = 2048 16B-chunks = 256 thr x 8; row=(tid>>3)+32*i,
    // chunk=(tid&7); pre-swizzled global chunk = (tid&7)^(row&7); linear dest.
    const size_t Kb = (size_t)Kdim * 2;
    const int sk = (((tid & 7) ^ ((tid >> 3) & 7)) << 4);
    const char* gA = Ae + (size_t)(tid >> 3) * Kb + sk;
    const char* gB = Be + (size_t)(tid >> 3) * Kb + sk;
    const int dst = tid * 16;

    #define STG(kt, buf) {                                                      \
        _Pragma("unroll")                                                       \
        for (int i = 0; i < 8; ++i)                                             \
            gload_lds16(gA + (size_t)(i * 32) * Kb + (size_t)(kt) * 128,        \
                        (char*)As + (buf) * 32768 + i * 4096 + dst);            \
        _Pragma("unroll")                                                       \
        for (int i = 0; i < 8; ++i)                                             \
            gload_lds16(gB + (size_t)(i * 32) * Kb + (size_t)(kt) * 128,        \
                        (char*)Bs + (buf) * 32768 + i * 4096 + dst); }

    f32x16 acc[4][4] = {};   // 16 tiles of 32x32, 256 VGPR

    // prologue
    STG(0, 0);
    asm volatile("s_waitcnt vmcnt(0)");
    __builtin_amdgcn_s_barrier();
    __builtin_amdgcn_sched_barrier(0);

    for (int kt = 0; kt < NKT; ++kt) {
        const int buf = kt & 1;
        if (kt + 1 < NKT) STG(kt + 1, buf ^ 1);
        const char* pa = (const char*)As + buf * 32768;
        const char* pb = (const char*)Bs + buf * 32768;
#pragma unroll
        for (int ks = 0; ks < 4; ++ks) {
            const int kb = (ks * 32 + kg * 16) ^ swz;
            bf16x8 aq[4], bq[4];
#pragma unroll
            for (int mt = 0; mt < 4; ++mt)
                aq[mt] = *(const bf16x8*)(pa + abase + mt * 4096 + kb);
#pragma unroll
            for (int nt = 0; nt < 4; ++nt)
                bq[nt] = *(const bf16x8*)(pb + bbase + nt * 4096 + kb);
#pragma unroll
            for (int mt = 0; mt < 4; ++mt)
#pragma unroll
                for (int nt = 0; nt < 4; ++nt)
                    acc[mt][nt] = __builtin_amdgcn_mfma_f32_32x32x16_bf16(
                        aq[mt], bq[nt], acc[mt][nt], 0, 0, 0);
        }
        asm volatile("s_waitcnt vmcnt(0)");   // stage(kt+1) issued ~2070 cyc ago
        __builtin_amdgcn_s_barrier();
        __builtin_amdgcn_sched_barrier(0);
    }

    // ---- epilogue. 32x32 C/D mapping (m74/m101): col = lane&31,
    // row = (r&3) + 8*(r>>2) + 4*(lane>>5), r in [0,16) ----
    const int crow0 = 4 * kg;
    if (MODE == 0) {
        unsigned short* Hp = Hout + (size_t)e * Mq * Ndim;
#pragma unroll
        for (int mt = 0; mt < 4; ++mt)
#pragma unroll
        for (int nt = 0; nt < 4; ++nt) {
            const int col = n0 + wc * 128 + nt * 32 + lr;
#pragma unroll
            for (int r = 0; r < 16; ++r) {
                int row = m0 + wr * 128 + mt * 32 + (r & 3) + 8 * (r >> 2) + crow0;
                Hp[(size_t)row * Ndim + col] = f2bf(fmaxf(acc[mt][nt][r], 0.f));
            }
        }
    } else {
#pragma unroll
        for (int mt = 0; mt < 4; ++mt)
#pragma unroll
        for (int r = 0; r < 16; ++r) {
            int rowl = wr * 128 + mt * 32 + (r & 3) + 8 * (r >> 2) + crow0;
            int tt = t_lds[rowl];
            if (tt < 0) continue;
            float g = g_lds[rowl];
#pragma unroll
            for (int nt = 0; nt < 4; ++nt) {
                int col = n0 + wc * 128 + nt * 32 + lr;
                Out[(size_t)tt * Dq + col] = g * acc[mt][nt][r];
            }
        }
    }
    #undef STG
}

// ---------------------------------------------------------------------------
extern "C" void kernel_launch(void* const* d_in, const int* in_sizes, int n_in,
                              void* d_out, int out_size, void* d_ws, size_t ws_size,
                              hipStream_t stream)
{
    const float* tok = (const float*)d_in[0];
    const float* Wg  = (const float*)d_in[1];
    const float* W1  = (const float*)d_in[2];
    const float* W2  = (const float*)d_in[3];
    float* out = (float*)d_out;
    char* ws = (char*)d_ws;

    // workspace layout (bytes)
    unsigned short* W1T = (unsigned short*)(ws);                    // [E][DFF][D] bf16  67108864
    unsigned short* W2T = (unsigned short*)(ws + 67108864);         // [E][D][DFF] bf16  67108864
    unsigned short* X   = (unsigned short*)(ws + 134217728);        // [E][M][D]  bf16   41943040
    unsigned short* H   = (unsigned short*)(ws + 176160768);        // [E][M][DFF] bf16 167772160
    int*   tfs  = (int*)(ws + 343932928);                           // [E][M]            81920
    int*   eidx = (int*)(ws + 344014848);                           // [T]               65536
    float* gate = (float*)(ws + 344080384);                         // [T]               65536

    hipMemsetAsync(tfs, 0xFF, Eq * Mq * 4, stream);

    route_kernel<<<Tq / 4, 256, 0, stream>>>(tok, Wg, eidx, gate);
    slot_kernel<<<Bq * Eq, 64, 0, stream>>>(eidx, tfs, out);
    dispatch_kernel<<<Eq * Mq, 128, 0, stream>>>(tok, tfs, X);
    transpose_cvt<<<dim3(DFFq / 32, Dq / 32, Eq), 256, 0, stream>>>(W1, W1T, Dq, DFFq);
    transpose_cvt<<<dim3(Dq / 32, DFFq / 32, Eq), 256, 0, stream>>>(W2, W2T, DFFq, Dq);

    // GEMM1: H = relu(X @ W1): 10 x 16 x 8 = 1280 blocks (5 exact CU rounds)
    gemmw<0, DFFq, Dq><<<(Mq / 256) * (DFFq / 256) * Eq, 256, 0, stream>>>(
        X, W1T, H, nullptr, nullptr, nullptr);
    // GEMM2: out[token] = gate * (H @ W2): 10 x 4 x 8 = 320 blocks
    gemmw<1, Dq, DFFq><<<(Mq / 256) * (Dq / 256) * Eq, 256, 0, stream>>>(
        H, W2T, nullptr, out, tfs, gate);
}

// Round 10
// 659.018 us; speedup vs baseline: 1.1371x; 1.1371x over previous
//
#include <hip/hip_runtime.h>

// MoE switch layer: B=8, N=2048, D=1024, E=8, DFF=4096, CAP=320
#define Bq 8
#define Nq 2048
#define Dq 1024
#define Eq 8
#define DFFq 4096
#define CAPq 320
#define Mq (Bq * CAPq)   // 2560 rows per expert
#define Tq (Bq * Nq)     // 16384 tokens

typedef __attribute__((ext_vector_type(8))) short bf16x8;
typedef __attribute__((ext_vector_type(4))) float f32x4;

static __device__ __forceinline__ unsigned short f2bf(float f) {
    union { float f; unsigned u; } v;
    v.f = f;
    unsigned r = v.u + 0x7fffu + ((v.u >> 16) & 1u);   // RNE
    return (unsigned short)(r >> 16);
}

static __device__ __forceinline__ void gload_lds16(const void* g, void* l) {
    __builtin_amdgcn_global_load_lds(
        (const __attribute__((address_space(1))) unsigned int*)g,
        (__attribute__((address_space(3))) unsigned int*)l, 16, 0, 0);
}

// ---------------- routing: logits -> softmax -> argmax/gate ----------------
__global__ __launch_bounds__(256) void route_kernel(
    const float* __restrict__ tok, const float* __restrict__ Wg,
    int* __restrict__ eidx, float* __restrict__ gate)
{
    int wv = threadIdx.x >> 6, lane = threadIdx.x & 63;
    int t = blockIdx.x * 4 + wv;
    const float* tp = tok + (size_t)t * Dq;
    float acc[8] = {0.f,0.f,0.f,0.f,0.f,0.f,0.f,0.f};
    for (int it = 0; it < Dq / 64; ++it) {
        int d = it * 64 + lane;
        float x = tp[d];
        const float4* w = (const float4*)(Wg + (size_t)d * 8);
        float4 w0 = w[0], w1 = w[1];
        acc[0] += x * w0.x; acc[1] += x * w0.y; acc[2] += x * w0.z; acc[3] += x * w0.w;
        acc[4] += x * w1.x; acc[5] += x * w1.y; acc[6] += x * w1.z; acc[7] += x * w1.w;
    }
#pragma unroll
    for (int e = 0; e < 8; ++e)
#pragma unroll
        for (int off = 32; off; off >>= 1)
            acc[e] += __shfl_xor(acc[e], off, 64);
    if (lane == 0) {
        float m = acc[0]; int bi = 0;
#pragma unroll
        for (int e = 1; e < 8; ++e) if (acc[e] > m) { m = acc[e]; bi = e; }
        float s = 0.f;
#pragma unroll
        for (int e = 0; e < 8; ++e) s += expf(acc[e] - m);
        eidx[t] = bi;
        gate[t] = 1.0f / s;   // max prob
    }
}

// ------------- slot assignment + zero dropped-token output rows ------------
__global__ __launch_bounds__(64) void slot_kernel(
    const int* __restrict__ eidx, int* __restrict__ tfs,
    float* __restrict__ out)
{
    int b = blockIdx.x >> 3, e = blockIdx.x & 7;
    int lane = threadIdx.x;
    const int* ip = eidx + (size_t)b * Nq;
    int base = (e * Bq + b) * CAPq;
    int cnt = 0;
    for (int it = 0; it < Nq / 64; ++it) {
        int n = it * 64 + lane;
        bool my = (ip[n] == e);
        unsigned long long mask = __ballot(my);
        if (my) {
            int pos = cnt + __popcll(mask & ((1ull << lane) - 1ull));
            if (pos < CAPq) {
                tfs[base + pos] = b * Nq + n;
            } else {
                // dropped token: its output row must be zero
                float4 z = {0.f, 0.f, 0.f, 0.f};
                float4* op = (float4*)(out + (size_t)(b * Nq + n) * Dq);
                for (int q = 0; q < Dq / 4; ++q) op[q] = z;
            }
        }
        cnt += __popcll(mask);
    }
}

// ------------- dispatch: gather token rows -> bf16 expert buffers ----------
__global__ __launch_bounds__(128) void dispatch_kernel(
    const float* __restrict__ tok, const int* __restrict__ tfs,
    unsigned short* __restrict__ X)
{
    int r = blockIdx.x;          // 0 .. E*B*CAP-1
    int t = tfs[r];
    int d0 = threadIdx.x * 8;
    unsigned short o[8];
    if (t < 0) {
#pragma unroll
        for (int k = 0; k < 8; ++k) o[k] = 0;
    } else {
        const float4* p = (const float4*)(tok + (size_t)t * Dq + d0);
        float4 a = p[0], b = p[1];
        o[0]=f2bf(a.x); o[1]=f2bf(a.y); o[2]=f2bf(a.z); o[3]=f2bf(a.w);
        o[4]=f2bf(b.x); o[5]=f2bf(b.y); o[6]=f2bf(b.z); o[7]=f2bf(b.w);
    }
    *(uint4*)(X + (size_t)r * Dq + d0) = *(const uint4*)o;
}

// ------- weight transpose+convert: in [E][R][C] f32 -> out [E][C][R] bf16 --
__global__ __launch_bounds__(256) void transpose_cvt(
    const float* __restrict__ in, unsigned short* __restrict__ out,
    int R, int C)
{
    __shared__ float tile[32][33];
    int e = blockIdx.z;
    int c0 = blockIdx.x * 32, r0 = blockIdx.y * 32;
    int tx = threadIdx.x & 31, ty = threadIdx.x >> 5;
    const float* ip = in + (size_t)e * R * C;
#pragma unroll
    for (int rr = 0; rr < 4; ++rr)
        tile[ty + rr * 8][tx] = ip[(size_t)(r0 + ty + rr * 8) * C + c0 + tx];
    __syncthreads();
    unsigned short* op = out + (size_t)e * R * C;
#pragma unroll
    for (int rr = 0; rr < 4; ++rr)
        op[(size_t)(c0 + ty + rr * 8) * R + r0 + tx] = f2bf(tile[tx][ty + rr * 8]);
}

// ====== 128x128 NT GEMM, BK=64, double-buffered, 2 blocks/CU ===============
// C[M][N] = A[M][K] * Bt[N][K]^T per expert. 256 thr = 4 waves (2M x 2N),
// per-wave 64x64 (round-1 verified core: swizzle, frags, epilogue, 0 bank
// conflicts). LDS double-buffer (66 KB -> 2 blocks/CU) with the wait ledger:
// stage tile kt+2 AFTER the K-tile barrier (WAR-safe: all reads of that
// buffer executed pre-barrier), so each vmcnt(0) retires loads issued exactly
// ONE BODY earlier -> L2(~200cyc) covered, cross-block stagger absorbs rest.
// STG takes a TILE INDEX (1 tile = 64 k-elems = 128 bytes).  [r9 bug: callers
// passed element offsets into a x128-byte macro -> staged k=4096 garbage]
// MODE 0: H = relu(C) as bf16.  MODE 1: scatter rows to Out with gate.
template <int MODE>
__global__ __launch_bounds__(256, 2) void gemm_nt(
    const unsigned short* __restrict__ A,   // [E][M][K] bf16
    const unsigned short* __restrict__ Bt,  // [E][N][K] bf16
    unsigned short* __restrict__ Hout,      // [E][M][N] bf16  (MODE 0)
    float* __restrict__ Out,                // [T][D] f32      (MODE 1)
    const int* __restrict__ tfs,            // [E][M]
    const float* __restrict__ gate,         // [T]
    int M, int N, int K)
{
    __shared__ __align__(16) unsigned short As[2][128 * 64];  // 32 KiB
    __shared__ __align__(16) unsigned short Bs[2][128 * 64];  // 32 KiB
    __shared__ int   t_lds[128];
    __shared__ float g_lds[128];

    const int tid = threadIdx.x;

    // XCD-aware bijective swizzle (grid % 8 == 0 for both GEMMs)
    const int NTB = N >> 7;
    const int MT  = M >> 7;
    const int nwg = MT * NTB * Eq;
    int flat = blockIdx.x;
    int wg = (flat & 7) * (nwg >> 3) + (flat >> 3);
    int e   = wg / (MT * NTB);
    int rem = wg - e * (MT * NTB);
    int mb = rem / NTB, nb = rem - mb * NTB;
    const int m0 = mb << 7, n0 = nb << 7;

    const unsigned short* Ae = A  + (size_t)e * M * K + (size_t)m0 * K;
    const unsigned short* Be = Bt + (size_t)e * N * K + (size_t)n0 * K;

    if (MODE == 1) {
        if (tid < 128) {
            int t = tfs[e * M + m0 + tid];
            t_lds[tid] = t;
            g_lds[tid] = (t >= 0) ? gate[t] : 0.f;
        }
        __syncthreads();   // drain t_lds loads -> clean vmcnt ledger
    }

    const int lane = tid & 63;
    const int wv = tid >> 6;
    const int wr = wv >> 1, wc = wv & 1;
    const int lrow = lane & 15;
    const int lk = lane >> 4;
    const int swz = (lrow & 7) << 4;

    // staging decode (r1-verified): row = tid>>3, pre-swizzled chunk
    const int srow = tid >> 3;
    const int skb  = ((tid & 7) << 4) ^ (((tid >> 3) & 7) << 4);
    const int ldst = (tid >> 6) << 10;                 // wave-uniform dest

    const char* gAb = (const char*)Ae + ((size_t)srow * K) * 2 + skb;
    const char* gBb = (const char*)Be + ((size_t)srow * K) * 2 + skb;

    // tile = K-tile index; byte offset = tile * 64 elems * 2B = tile * 128
    #define STG(tile, buf) {                                                   \
        const char* _ga = gAb + (size_t)(tile) * 128;                          \
        const char* _gb = gBb + (size_t)(tile) * 128;                          \
        char* _la = (char*)As + (buf) * 16384 + ldst;                          \
        char* _lb = (char*)Bs + (buf) * 16384 + ldst;                          \
        _Pragma("unroll")                                                      \
        for (int _i = 0; _i < 4; ++_i) {                                       \
            gload_lds16(_ga + (size_t)(_i * 32) * K * 2, _la + _i * 4096);     \
            gload_lds16(_gb + (size_t)(_i * 32) * K * 2, _lb + _i * 4096);     \
        } }

    f32x4 acc[4][4] = {};
    const int NK = K >> 6;

    // prologue: stage tile0 -> buf0, tile1 -> buf1; wait tile0 resident
    STG(0, 0);
    STG(1, 1);
    asm volatile("s_waitcnt vmcnt(8)");
    __builtin_amdgcn_s_barrier();
    __builtin_amdgcn_sched_barrier(0);

    for (int kt = 0; kt < NK; ++kt) {
        const int buf = kt & 1;
        const char* pa = (const char*)As + buf * 16384;
        const char* pb = (const char*)Bs + buf * 16384;
#pragma unroll
        for (int kk = 0; kk < 2; ++kk) {
            bf16x8 af[4], bfr[4];
#pragma unroll
            for (int i = 0; i < 4; ++i) {
                int row = wr * 64 + i * 16 + lrow;
                int addr = row * 128 + ((kk * 64 + lk * 16) ^ swz);
                af[i] = *(const bf16x8*)(pa + addr);
            }
#pragma unroll
            for (int j = 0; j < 4; ++j) {
                int row = wc * 64 + j * 16 + lrow;
                int addr = row * 128 + ((kk * 64 + lk * 16) ^ swz);
                bfr[j] = *(const bf16x8*)(pb + addr);
            }
            __builtin_amdgcn_s_setprio(1);
#pragma unroll
            for (int i = 0; i < 4; ++i)
#pragma unroll
                for (int j = 0; j < 4; ++j)
                    acc[i][j] = __builtin_amdgcn_mfma_f32_16x16x32_bf16(
                        af[i], bfr[j], acc[i][j], 0, 0, 0);
            __builtin_amdgcn_s_setprio(0);
        }
        if (kt + 1 < NK) {
            // retire tile kt+1's stages: issued one full body ago -> covered
            asm volatile("s_waitcnt vmcnt(0)");
            __builtin_amdgcn_s_barrier();
            __builtin_amdgcn_sched_barrier(0);
            if (kt + 2 < NK) STG(kt + 2, buf);   // after barrier: WAR-safe
        }
    }

    if (MODE == 0) {
        unsigned short* Hp = Hout + (size_t)e * M * N;
#pragma unroll
        for (int i = 0; i < 4; ++i) {
            int row = m0 + wr * 64 + i * 16 + lk * 4;
#pragma unroll
            for (int j = 0; j < 4; ++j) {
                int col = n0 + wc * 64 + j * 16 + lrow;
#pragma unroll
                for (int r = 0; r < 4; ++r)
                    Hp[(size_t)(row + r) * N + col] = f2bf(fmaxf(acc[i][j][r], 0.f));
            }
        }
    } else {
#pragma unroll
        for (int i = 0; i < 4; ++i) {
            int rowl = wr * 64 + i * 16 + lk * 4;
#pragma unroll
            for (int r = 0; r < 4; ++r) {
                int t = t_lds[rowl + r];
                if (t < 0) continue;
                float g = g_lds[rowl + r];
#pragma unroll
                for (int j = 0; j < 4; ++j) {
                    int col = n0 + wc * 64 + j * 16 + lrow;
                    Out[(size_t)t * Dq + col] = g * acc[i][j][r];
                }
            }
        }
    }
    #undef STG
}

// ---------------------------------------------------------------------------
extern "C" void kernel_launch(void* const* d_in, const int* in_sizes, int n_in,
                              void* d_out, int out_size, void* d_ws, size_t ws_size,
                              hipStream_t stream)
{
    const float* tok = (const float*)d_in[0];
    const float* Wg  = (const float*)d_in[1];
    const float* W1  = (const float*)d_in[2];
    const float* W2  = (const float*)d_in[3];
    float* out = (float*)d_out;
    char* ws = (char*)d_ws;

    // workspace layout (bytes)
    unsigned short* W1T = (unsigned short*)(ws);                    // [E][DFF][D] bf16  67108864
    unsigned short* W2T = (unsigned short*)(ws + 67108864);         // [E][D][DFF] bf16  67108864
    unsigned short* X   = (unsigned short*)(ws + 134217728);        // [E][M][D]  bf16   41943040
    unsigned short* H   = (unsigned short*)(ws + 176160768);        // [E][M][DFF] bf16 167772160
    int*   tfs  = (int*)(ws + 343932928);                           // [E][M]            81920
    int*   eidx = (int*)(ws + 344014848);                           // [T]               65536
    float* gate = (float*)(ws + 344080384);                         // [T]               65536

    hipMemsetAsync(tfs, 0xFF, Eq * Mq * 4, stream);

    route_kernel<<<Tq / 4, 256, 0, stream>>>(tok, Wg, eidx, gate);
    slot_kernel<<<Bq * Eq, 64, 0, stream>>>(eidx, tfs, out);
    dispatch_kernel<<<Eq * Mq, 128, 0, stream>>>(tok, tfs, X);
    transpose_cvt<<<dim3(DFFq / 32, Dq / 32, Eq), 256, 0, stream>>>(W1, W1T, Dq, DFFq);
    transpose_cvt<<<dim3(Dq / 32, DFFq / 32, Eq), 256, 0, stream>>>(W2, W2T, DFFq, Dq);

    // GEMM1: H = relu(X @ W1): 20 x 32 x 8 = 5120 blocks @ 2/CU = 10 rounds
    gemm_nt<0><<<(Mq / 128) * (DFFq / 128) * Eq, 256, 0, stream>>>(
        X, W1T, H, nullptr, nullptr, nullptr, Mq, DFFq, Dq);
    // GEMM2: out[token] = gate * (H @ W2): 20 x 8 x 8 = 1280 blocks = 2.5 rounds
    gemm_nt<1><<<(Mq / 128) * (Dq / 128) * Eq, 256, 0, stream>>>(
        H, W2T, nullptr, out, tfs, gate, Mq, Dq, DFFq);
}